// Round 7
// baseline (172.849 us; speedup 1.0000x reference)
//
#include <hip/hip_runtime.h>
#include <hip/hip_bf16.h>
#include <hip/hip_cooperative_groups.h>
#include <cstdint>

namespace cg = cooperative_groups;

#define B_SZ  4096
#define N_POS 512
#define N_CLS 512
#define PHI   128
#define H1D   512
#define H2D   256

#define HS 520   // hist/h1 LDS row stride in bf16 (512+8: bank-conflict-free)
#define US 136   // u LDS row stride in bf16 (128+8)

typedef short bf16x8 __attribute__((ext_vector_type(8)));
typedef float f32x4  __attribute__((ext_vector_type(4)));

__device__ __forceinline__ unsigned int bf16rne(float f) {
  unsigned int x = __float_as_uint(f);
  return (x + 0x7fffu + ((x >> 16) & 1u)) >> 16;
}

// ---------------------------------------------------------------------------
// One cooperative kernel, 256 blocks x 512 threads (1 block/CU co-resident).
// Stage A (prep): bf16 transposed weights WphiT/W1T/W2T into ws (2 elem/thr)
//   + b1eff[j] = b1[j] + 512*(b_phi @ W1[:,j]) (one wave per j, fp32).
// grid.sync()
// Stage B (fused, per block = 16 batch rows):
//   hist (LDS atomics) -> u = Hist@WphiT^T -> h1 = relu(u@W1T^T + b1eff)
//   -> h2 = relu(h1@W2T^T + b2) -> out = h2@W3 + b3
// Hist/u/h1 live only in LDS. 8 waves split columns (ph1: 16/wave,
// ph2: 64/wave, ph3: 32/wave) -> 2 waves/SIMD latency hiding.
// MFMA 16x16x32: A-frag m=lane&15, k=(lane>>4)*8+i; C/D col=lane&15,
// row=(lane>>4)*4+reg.
// ---------------------------------------------------------------------------
__global__ __launch_bounds__(512) void deepset_coop(
    const int* __restrict__ x, const float* __restrict__ W_phi,
    const float* __restrict__ W1, const float* __restrict__ W2,
    const float* __restrict__ b_phi, const float* __restrict__ b1,
    const float* __restrict__ b2, const float* __restrict__ W3,
    const float* __restrict__ b3,
    unsigned short* __restrict__ WphiT, unsigned short* __restrict__ W1T,
    unsigned short* __restrict__ W2T, float* __restrict__ b1eff,
    float* __restrict__ out) {
  __shared__ unsigned int   hs[16 * 512];       // 32 KB
  __shared__ unsigned short hist_bf[16 * HS];   // 16.25 KB
  __shared__ unsigned short u_bf[16 * US];      // 4.25 KB
  __shared__ unsigned short h1_bf[16 * HS];     // 16.25 KB
  __shared__ float red[8][16];

  const int tid = threadIdx.x;
  const int blk = blockIdx.x;
  const int w = tid >> 6, l = tid & 63;
  const int r = l & 15, q = l >> 4;
  const int bm = blk * 16;

  // ================= stage A: weight prep =================
  #pragma unroll
  for (int i = 0; i < 2; ++i) {
    int e = blk * 1024 + i * 512 + tid;   // 0 .. 262143
    if (e < 65536) {                      // WphiT[n][c] = W_phi[c][n]
      int n = e >> 9, c = e & 511;
      WphiT[e] = (unsigned short)bf16rne(W_phi[c * PHI + n]);
    } else if (e < 131072) {              // W1T[j][p] = W1[p][j]
      int o = e - 65536;
      int j = o >> 7, p = o & 127;
      W1T[o] = (unsigned short)bf16rne(W1[p * H1D + j]);
    } else {                              // W2T[n][k] = W2[k][n]
      int o = e - 131072;
      int n = o >> 9, k = o & 511;
      W2T[o] = (unsigned short)bf16rne(W2[k * H2D + n]);
    }
  }
  {
    // b1eff: global wave g < 512 computes column g
    const int g = blk * 8 + w;
    if (g < H1D) {
      float a = b_phi[l] * W1[(size_t)l * H1D + g] +
                b_phi[l + 64] * W1[(size_t)(l + 64) * H1D + g];
      #pragma unroll
      for (int off = 32; off > 0; off >>= 1) a += __shfl_down(a, off, 64);
      if (l == 0) b1eff[g] = b1[g] + 512.0f * a;
    }
  }
  __threadfence();
  cg::this_grid().sync();

  // ================= stage B: fused forward =================
  // ---- phase 0: histogram of 16 rows (32 threads/row, 16 positions each) ----
  uint4* hs4 = (uint4*)hs;
  #pragma unroll
  for (int i = 0; i < 4; ++i) hs4[tid * 4 + i] = make_uint4(0, 0, 0, 0);
  __syncthreads();
  {
    const int row = tid >> 5, sub = tid & 31;
    const int* xp = x + (size_t)(bm + row) * N_POS + sub * 16;
    #pragma unroll
    for (int i = 0; i < 4; ++i) {
      int4 c = *(const int4*)(xp + i * 4);
      atomicAdd(&hs[row * 512 + c.x], 1u);
      atomicAdd(&hs[row * 512 + c.y], 1u);
      atomicAdd(&hs[row * 512 + c.z], 1u);
      atomicAdd(&hs[row * 512 + c.w], 1u);
    }
  }
  __syncthreads();
  {
    const int row = tid >> 5, sub = tid & 31;
    const unsigned int* src = hs + row * 512 + sub * 16;
    unsigned short* dst = hist_bf + row * HS + sub * 16;
    #pragma unroll
    for (int i = 0; i < 2; ++i) {
      uint4 a = *(const uint4*)(src + i * 8);
      uint4 bq = *(const uint4*)(src + i * 8 + 4);
      uint4 o;
      o.x = bf16rne((float)a.x)  | (bf16rne((float)a.y)  << 16);
      o.y = bf16rne((float)a.z)  | (bf16rne((float)a.w)  << 16);
      o.z = bf16rne((float)bq.x) | (bf16rne((float)bq.y) << 16);
      o.w = bf16rne((float)bq.z) | (bf16rne((float)bq.w) << 16);
      *(uint4*)(dst + i * 8) = o;
    }
  }
  __syncthreads();

  // ---- phase 1: u = Hist @ WphiT^T  (K=512, N=128; wave w -> cols 16w..16w+15)
  f32x4 accu = (f32x4){0.f, 0.f, 0.f, 0.f};
  #pragma unroll 4
  for (int k0 = 0; k0 < N_CLS; k0 += 32) {
    bf16x8 af = *(const bf16x8*)&hist_bf[r * HS + k0 + q * 8];
    bf16x8 bfr = *(const bf16x8*)(WphiT + (size_t)(16 * w + r) * N_CLS + k0 + q * 8);
    accu = __builtin_amdgcn_mfma_f32_16x16x32_bf16(af, bfr, accu, 0, 0, 0);
  }
  #pragma unroll
  for (int reg = 0; reg < 4; ++reg)
    u_bf[(q * 4 + reg) * US + 16 * w + r] = (unsigned short)bf16rne(accu[reg]);
  __syncthreads();

  // ---- phase 2: h1 = relu(u @ W1T^T + b1eff)  (K=128, N=512; wave w -> cols 64w..)
  f32x4 acc1[4];
  #pragma unroll
  for (int j = 0; j < 4; ++j) acc1[j] = (f32x4){0.f, 0.f, 0.f, 0.f};
  #pragma unroll
  for (int k0 = 0; k0 < PHI; k0 += 32) {
    bf16x8 af = *(const bf16x8*)&u_bf[r * US + k0 + q * 8];
    #pragma unroll
    for (int tt = 0; tt < 4; ++tt) {
      bf16x8 bfr = *(const bf16x8*)(W1T + (size_t)(64 * w + 16 * tt + r) * PHI + k0 + q * 8);
      acc1[tt] = __builtin_amdgcn_mfma_f32_16x16x32_bf16(af, bfr, acc1[tt], 0, 0, 0);
    }
  }
  #pragma unroll
  for (int tt = 0; tt < 4; ++tt) {
    const int col = 64 * w + 16 * tt + r;
    const float bv = b1eff[col];
    #pragma unroll
    for (int reg = 0; reg < 4; ++reg) {
      float v = fmaxf(acc1[tt][reg] + bv, 0.0f);
      h1_bf[(q * 4 + reg) * HS + col] = (unsigned short)bf16rne(v);
    }
  }
  __syncthreads();

  // ---- phase 3: h2 = relu(h1 @ W2T^T + b2); out = h2 @ W3 + b3
  //      (K=512, N=256; wave w -> cols 32w..32w+31)
  f32x4 acc2[2];
  acc2[0] = (f32x4){0.f, 0.f, 0.f, 0.f};
  acc2[1] = (f32x4){0.f, 0.f, 0.f, 0.f};
  #pragma unroll 4
  for (int k0 = 0; k0 < H1D; k0 += 32) {
    bf16x8 af = *(const bf16x8*)&h1_bf[r * HS + k0 + q * 8];
    #pragma unroll
    for (int tt = 0; tt < 2; ++tt) {
      bf16x8 bfr = *(const bf16x8*)(W2T + (size_t)(32 * w + 16 * tt + r) * H1D + k0 + q * 8);
      acc2[tt] = __builtin_amdgcn_mfma_f32_16x16x32_bf16(af, bfr, acc2[tt], 0, 0, 0);
    }
  }
  float part[4] = {0.f, 0.f, 0.f, 0.f};
  #pragma unroll
  for (int tt = 0; tt < 2; ++tt) {
    const int col = 32 * w + 16 * tt + r;
    const float bv = b2[col];
    const float w3 = W3[col];
    #pragma unroll
    for (int reg = 0; reg < 4; ++reg)
      part[reg] += fmaxf(acc2[tt][reg] + bv, 0.0f) * w3;
  }
  #pragma unroll
  for (int off = 1; off < 16; off <<= 1)
    #pragma unroll
    for (int reg = 0; reg < 4; ++reg)
      part[reg] += __shfl_xor(part[reg], off, 64);
  if (r == 0)
    #pragma unroll
    for (int reg = 0; reg < 4; ++reg) red[w][q * 4 + reg] = part[reg];
  __syncthreads();
  if (tid < 16) {
    float s = b3[0];
    #pragma unroll
    for (int ww = 0; ww < 8; ++ww) s += red[ww][tid];
    out[bm + tid] = s;
  }
}

// ---------------------------------------------------------------------------
extern "C" void kernel_launch(void* const* d_in, const int* in_sizes, int n_in,
                              void* d_out, int out_size, void* d_ws, size_t ws_size,
                              hipStream_t stream) {
  const int*   x     = (const int*)  d_in[0];
  const float* W_phi = (const float*)d_in[1];
  const float* b_phi = (const float*)d_in[2];
  const float* W1    = (const float*)d_in[3];
  const float* b1    = (const float*)d_in[4];
  const float* W2    = (const float*)d_in[5];
  const float* b2    = (const float*)d_in[6];
  const float* W3    = (const float*)d_in[7];
  const float* b3    = (const float*)d_in[8];
  float* out = (float*)d_out;

  char* ws = (char*)d_ws;
  unsigned short* WphiT = (unsigned short*)(ws);            // 128 KB
  unsigned short* W1T   = (unsigned short*)(ws + 131072);   // 128 KB
  unsigned short* W2T   = (unsigned short*)(ws + 262144);   // 256 KB
  float*          b1eff = (float*)         (ws + 524288);   // 2 KB

  void* args[] = {
    (void*)&x, (void*)&W_phi, (void*)&W1, (void*)&W2, (void*)&b_phi,
    (void*)&b1, (void*)&b2, (void*)&W3, (void*)&b3,
    (void*)&WphiT, (void*)&W1T, (void*)&W2T, (void*)&b1eff, (void*)&out
  };
  hipLaunchCooperativeKernel((const void*)deepset_coop,
                             dim3(B_SZ / 16), dim3(512), args, 0, stream);
}

// Round 8
// 95.410 us; speedup vs baseline: 1.8116x; 1.8116x over previous
//
#include <hip/hip_runtime.h>
#include <hip/hip_bf16.h>
#include <cstdint>

#define B_SZ  4096
#define N_POS 512
#define N_CLS 512
#define PHI   128
#define H1D   512
#define H2D   256

#define HS 520   // hist/h1 LDS row stride in bf16 (512+8: bank-conflict-free)
#define US 136   // u LDS row stride in bf16 (128+8)

typedef short bf16x8 __attribute__((ext_vector_type(8)));
typedef float f32x4  __attribute__((ext_vector_type(4)));

__device__ __forceinline__ unsigned int bf16rne(float f) {
  unsigned int x = __float_as_uint(f);
  return (x + 0x7fffu + ((x >> 16) & 1u)) >> 16;
}

// ---------------------------------------------------------------------------
// prep: bf16 transposed weights + fp32 effective bias. grid 1026 x 256.
//  blocks 0..255    : WphiT[n][c] = bf16(W_phi[c][n])   (128 x 512)
//  blocks 256..511  : W1T[j][p]   = bf16(W1[p][j])      (512 x 128)
//  blocks 512..1023 : W2T[n][k]   = bf16(W2[k][n])      (256 x 512)
//  blocks 1024..1025: b1eff[j]    = b1[j] + 512*(b_phi @ W1[:,j])  (fp32)
// NOTE (R7 post-mortem): do NOT merge this into `fused` via grid.sync() —
// cooperative grid barrier on gfx950 costs ~70 µs (MfmaUtil 1%, idle spin
// across non-coherent XCD L2s). A kernel boundary is the cheap barrier here.
// ---------------------------------------------------------------------------
__global__ __launch_bounds__(256) void prep(
    const float* __restrict__ W_phi, const float* __restrict__ W1,
    const float* __restrict__ W2, const float* __restrict__ b_phi,
    const float* __restrict__ b1,
    unsigned short* __restrict__ WphiT, unsigned short* __restrict__ W1T,
    unsigned short* __restrict__ W2T, float* __restrict__ b1eff) {
  const int b = blockIdx.x, tid = threadIdx.x;
  if (b < 256) {
    int o = b * 256 + tid;
    int n = o >> 9, c = o & 511;
    WphiT[o] = (unsigned short)bf16rne(W_phi[c * PHI + n]);
  } else if (b < 512) {
    int o = (b - 256) * 256 + tid;
    int j = o >> 7, p = o & 127;
    W1T[o] = (unsigned short)bf16rne(W1[p * H1D + j]);
  } else if (b < 1024) {
    int o = (b - 512) * 256 + tid;
    int n = o >> 9, k = o & 511;
    W2T[o] = (unsigned short)bf16rne(W2[k * H2D + n]);
  } else {
    int j = (b - 1024) * 256 + tid;
    float a = 0.0f;
    #pragma unroll 8
    for (int p = 0; p < PHI; ++p) a += b_phi[p] * W1[p * H1D + j];
    b1eff[j] = b1[j] + 512.0f * a;
  }
}

// ---------------------------------------------------------------------------
// fused: per block of 16 batch rows (256 blocks, 512 threads = 8 waves):
//   hist (LDS atomics) -> u = Hist@WphiT^T -> h1 = relu(u@W1T^T + b1eff)
//   -> h2 = relu(h1@W2T^T + b2) -> out = h2@W3 + b3
// Hist/u/h1 live only in LDS. 8 waves split the column ranges (ph1: 16/wave,
// ph2: 64/wave, ph3: 32/wave) -> 2 waves/SIMD for latency hiding.
// MFMA 16x16x32: A-frag m=lane&15, k=(lane>>4)*8+i; C/D col=lane&15,
// row=(lane>>4)*4+reg.
// ---------------------------------------------------------------------------
__global__ __launch_bounds__(512) void fused(
    const int* __restrict__ x,
    const unsigned short* __restrict__ WphiT,
    const unsigned short* __restrict__ W1T,
    const unsigned short* __restrict__ W2T,
    const float* __restrict__ b1eff, const float* __restrict__ b2,
    const float* __restrict__ W3, const float* __restrict__ b3,
    float* __restrict__ out) {
  __shared__ unsigned int   hs[16 * 512];       // 32 KB
  __shared__ unsigned short hist_bf[16 * HS];   // 16.25 KB
  __shared__ unsigned short u_bf[16 * US];      // 4.25 KB
  __shared__ unsigned short h1_bf[16 * HS];     // 16.25 KB
  __shared__ float red[8][16];

  const int tid = threadIdx.x;
  const int w = tid >> 6, l = tid & 63;
  const int r = l & 15, q = l >> 4;
  const int bm = blockIdx.x * 16;

  // ---- phase 0: histogram of 16 rows (32 threads/row, 16 positions each) ----
  uint4* hs4 = (uint4*)hs;
  #pragma unroll
  for (int i = 0; i < 4; ++i) hs4[tid * 4 + i] = make_uint4(0, 0, 0, 0);
  __syncthreads();
  {
    const int row = tid >> 5, sub = tid & 31;
    const int* xp = x + (size_t)(bm + row) * N_POS + sub * 16;
    #pragma unroll
    for (int i = 0; i < 4; ++i) {
      int4 c = *(const int4*)(xp + i * 4);
      atomicAdd(&hs[row * 512 + c.x], 1u);
      atomicAdd(&hs[row * 512 + c.y], 1u);
      atomicAdd(&hs[row * 512 + c.z], 1u);
      atomicAdd(&hs[row * 512 + c.w], 1u);
    }
  }
  __syncthreads();
  {
    // counts <= 512 always -> bf16 exact
    const int row = tid >> 5, sub = tid & 31;
    const unsigned int* src = hs + row * 512 + sub * 16;
    unsigned short* dst = hist_bf + row * HS + sub * 16;
    #pragma unroll
    for (int i = 0; i < 2; ++i) {
      uint4 a = *(const uint4*)(src + i * 8);
      uint4 bq = *(const uint4*)(src + i * 8 + 4);
      uint4 o;
      o.x = bf16rne((float)a.x)  | (bf16rne((float)a.y)  << 16);
      o.y = bf16rne((float)a.z)  | (bf16rne((float)a.w)  << 16);
      o.z = bf16rne((float)bq.x) | (bf16rne((float)bq.y) << 16);
      o.w = bf16rne((float)bq.z) | (bf16rne((float)bq.w) << 16);
      *(uint4*)(dst + i * 8) = o;
    }
  }
  __syncthreads();

  // ---- phase 1: u = Hist @ WphiT^T  (K=512, N=128; wave w -> cols 16w..16w+15)
  f32x4 accu = (f32x4){0.f, 0.f, 0.f, 0.f};
  #pragma unroll 4
  for (int k0 = 0; k0 < N_CLS; k0 += 32) {
    bf16x8 af = *(const bf16x8*)&hist_bf[r * HS + k0 + q * 8];
    bf16x8 bfr = *(const bf16x8*)(WphiT + (size_t)(16 * w + r) * N_CLS + k0 + q * 8);
    accu = __builtin_amdgcn_mfma_f32_16x16x32_bf16(af, bfr, accu, 0, 0, 0);
  }
  #pragma unroll
  for (int reg = 0; reg < 4; ++reg)
    u_bf[(q * 4 + reg) * US + 16 * w + r] = (unsigned short)bf16rne(accu[reg]);
  __syncthreads();

  // ---- phase 2: h1 = relu(u @ W1T^T + b1eff)  (K=128, N=512; wave w -> cols 64w..)
  f32x4 acc1[4];
  #pragma unroll
  for (int j = 0; j < 4; ++j) acc1[j] = (f32x4){0.f, 0.f, 0.f, 0.f};
  #pragma unroll
  for (int k0 = 0; k0 < PHI; k0 += 32) {
    bf16x8 af = *(const bf16x8*)&u_bf[r * US + k0 + q * 8];
    #pragma unroll
    for (int tt = 0; tt < 4; ++tt) {
      bf16x8 bfr = *(const bf16x8*)(W1T + (size_t)(64 * w + 16 * tt + r) * PHI + k0 + q * 8);
      acc1[tt] = __builtin_amdgcn_mfma_f32_16x16x32_bf16(af, bfr, acc1[tt], 0, 0, 0);
    }
  }
  #pragma unroll
  for (int tt = 0; tt < 4; ++tt) {
    const int col = 64 * w + 16 * tt + r;
    const float bv = b1eff[col];
    #pragma unroll
    for (int reg = 0; reg < 4; ++reg) {
      float v = fmaxf(acc1[tt][reg] + bv, 0.0f);
      h1_bf[(q * 4 + reg) * HS + col] = (unsigned short)bf16rne(v);
    }
  }
  __syncthreads();

  // ---- phase 3: h2 = relu(h1 @ W2T^T + b2); out = h2 @ W3 + b3
  //      (K=512, N=256; wave w -> cols 32w..32w+31)
  f32x4 acc2[2];
  acc2[0] = (f32x4){0.f, 0.f, 0.f, 0.f};
  acc2[1] = (f32x4){0.f, 0.f, 0.f, 0.f};
  #pragma unroll 4
  for (int k0 = 0; k0 < H1D; k0 += 32) {
    bf16x8 af = *(const bf16x8*)&h1_bf[r * HS + k0 + q * 8];
    #pragma unroll
    for (int tt = 0; tt < 2; ++tt) {
      bf16x8 bfr = *(const bf16x8*)(W2T + (size_t)(32 * w + 16 * tt + r) * H1D + k0 + q * 8);
      acc2[tt] = __builtin_amdgcn_mfma_f32_16x16x32_bf16(af, bfr, acc2[tt], 0, 0, 0);
    }
  }
  float part[4] = {0.f, 0.f, 0.f, 0.f};
  #pragma unroll
  for (int tt = 0; tt < 2; ++tt) {
    const int col = 32 * w + 16 * tt + r;
    const float bv = b2[col];
    const float w3 = W3[col];
    #pragma unroll
    for (int reg = 0; reg < 4; ++reg)
      part[reg] += fmaxf(acc2[tt][reg] + bv, 0.0f) * w3;
  }
  #pragma unroll
  for (int off = 1; off < 16; off <<= 1)
    #pragma unroll
    for (int reg = 0; reg < 4; ++reg)
      part[reg] += __shfl_xor(part[reg], off, 64);
  if (r == 0)
    #pragma unroll
    for (int reg = 0; reg < 4; ++reg) red[w][q * 4 + reg] = part[reg];
  __syncthreads();
  if (tid < 16) {
    float s = b3[0];
    #pragma unroll
    for (int ww = 0; ww < 8; ++ww) s += red[ww][tid];
    out[bm + tid] = s;
  }
}

// ---------------------------------------------------------------------------
extern "C" void kernel_launch(void* const* d_in, const int* in_sizes, int n_in,
                              void* d_out, int out_size, void* d_ws, size_t ws_size,
                              hipStream_t stream) {
  const int*   x     = (const int*)  d_in[0];
  const float* W_phi = (const float*)d_in[1];
  const float* b_phi = (const float*)d_in[2];
  const float* W1    = (const float*)d_in[3];
  const float* b1    = (const float*)d_in[4];
  const float* W2    = (const float*)d_in[5];
  const float* b2    = (const float*)d_in[6];
  const float* W3    = (const float*)d_in[7];
  const float* b3    = (const float*)d_in[8];
  float* out = (float*)d_out;

  char* ws = (char*)d_ws;
  unsigned short* WphiT = (unsigned short*)(ws);            // 128 KB
  unsigned short* W1T   = (unsigned short*)(ws + 131072);   // 128 KB
  unsigned short* W2T   = (unsigned short*)(ws + 262144);   // 256 KB
  float*          b1eff = (float*)         (ws + 524288);   // 2 KB

  prep<<<1026, 256, 0, stream>>>(W_phi, W1, W2, b_phi, b1,
                                 WphiT, W1T, W2T, b1eff);
  fused<<<B_SZ / 16, 512, 0, stream>>>(x, WphiT, W1T, W2T,
                                       b1eff, b2, W3, b3, out);
}